// Round 6
// baseline (10898.202 us; speedup 1.0000x reference)
//
#include <hip/hip_runtime.h>
#include <math.h>

#define HID   256
#define GATES 1024   // 4*HID
#define BATCH 64
#define SEQ   2048

typedef __attribute__((ext_vector_type(8))) short short8;
typedef __attribute__((ext_vector_type(4))) float f32x4;

// ---------------------------------------------------------------------------
// GEMM: out[r][g] = sum_k A_row(r)[k] * W[g][k] + bias[g]   (unchanged)
// ---------------------------------------------------------------------------
#define BM 128
#define BN 128
#define BK 16
#define LDP 132

__global__ __launch_bounds__(256, 2)
void xg_gemm(const float* __restrict__ A, const float* __restrict__ W,
             const float* __restrict__ bias, float* __restrict__ out,
             int a_bstride, int ch_log2)
{
    __shared__ float As[BK][LDP];
    __shared__ float Ws[BK][LDP];

    const int tid   = threadIdx.x;
    const int m_blk = blockIdx.x * BM;
    const int n_blk = blockIdx.y * BN;

    const int tn = (tid & 15) * 4;
    const int tm = (tid >> 4) * 4;

    float acc[8][8];
    #pragma unroll
    for (int i = 0; i < 8; ++i)
        #pragma unroll
        for (int j = 0; j < 8; ++j) acc[i][j] = 0.f;

    const int lrow = tid >> 2;
    const int lkc  = (tid & 3) * 4;
    const int CHm1 = (1 << ch_log2) - 1;

    for (int k0 = 0; k0 < HID; k0 += BK) {
        #pragma unroll
        for (int p = 0; p < 2; ++p) {
            int row = p * 64 + lrow;
            int r   = m_blk + row;
            int b   = r >> ch_log2;
            int t   = r & CHm1;
            const float4 a = *(const float4*)(A + (size_t)b * a_bstride +
                                              (size_t)t * HID + k0 + lkc);
            As[lkc + 0][row] = a.x;
            As[lkc + 1][row] = a.y;
            As[lkc + 2][row] = a.z;
            As[lkc + 3][row] = a.w;

            int g = n_blk + row;
            const float4 w = *(const float4*)(W + (size_t)g * HID + k0 + lkc);
            Ws[lkc + 0][row] = w.x;
            Ws[lkc + 1][row] = w.y;
            Ws[lkc + 2][row] = w.z;
            Ws[lkc + 3][row] = w.w;
        }
        __syncthreads();

        #pragma unroll
        for (int kk = 0; kk < BK; ++kk) {
            float4 a0 = *(const float4*)&As[kk][tm];
            float4 a1 = *(const float4*)&As[kk][tm + 64];
            float4 b0 = *(const float4*)&Ws[kk][tn];
            float4 b1 = *(const float4*)&Ws[kk][tn + 64];
            float av[8] = {a0.x, a0.y, a0.z, a0.w, a1.x, a1.y, a1.z, a1.w};
            float bv[8] = {b0.x, b0.y, b0.z, b0.w, b1.x, b1.y, b1.z, b1.w};
            #pragma unroll
            for (int i = 0; i < 8; ++i)
                #pragma unroll
                for (int j = 0; j < 8; ++j)
                    acc[i][j] += av[i] * bv[j];
        }
        __syncthreads();
    }

    const float4 bias0 = *(const float4*)&bias[n_blk + tn];
    const float4 bias1 = *(const float4*)&bias[n_blk + tn + 64];
    #pragma unroll
    for (int i = 0; i < 8; ++i) {
        int m  = (i < 4) ? (tm + i) : (tm + 60 + i);
        int gm = m_blk + m;
        float* op = out + (size_t)gm * GATES + n_blk;
        float4 v0 = {acc[i][0] + bias0.x, acc[i][1] + bias0.y,
                     acc[i][2] + bias0.z, acc[i][3] + bias0.w};
        float4 v1 = {acc[i][4] + bias1.x, acc[i][5] + bias1.y,
                     acc[i][6] + bias1.z, acc[i][7] + bias1.w};
        *(float4*)(op + tn)      = v0;
        *(float4*)(op + tn + 64) = v1;
    }
}

// ---------------------------------------------------------------------------
// Cooperative recurrence v5: MFMA, in-lane epilogue, ONE barrier/step.
// 256 wgs (slice s, batch b), 512 thr. Wave wv computes 2 MFMA m-tiles.
// Row remap: tile t, tile-row m  ->  gate (m&3) of unit (wv*8 + t*4 + (m>>2)),
// so C/D reg r of lane (q=quad) = gate r (i,f,g,o) of unit wv*8+t*4+q:
// the whole LSTM cell update happens in-lane (mcol==0 owners), no g_s LDS.
// h staging double-buffered by step parity -> single __syncthreads per step
// is race-free (stage(t+2) follows barrier(t+1) which follows all reads(t)).
// 6 independent MFMA accumulator chains of depth 8 hide MFMA latency.
// amdgpu_waves_per_eu(2,2) pins the VGPR budget at 256/lane so the 128
// weight-fragment VGPRs stay in architectural registers (R5: 128-reg alloc
// caused AGPR-shuffle + scratch spill, FETCH +14MB).
// ---------------------------------------------------------------------------
#define MBSTRIDE ((size_t)BATCH * HID)   // ulongs per parity block

__device__ __forceinline__ float sigmoid_f(float x) {
    return 1.f / (1.f + __expf(-x));
}
__device__ __forceinline__ float tanh_f(float x) {
    return 1.f - 2.f / (1.f + __expf(2.f * x));
}
__device__ __forceinline__ unsigned short f2bf_rne(float f) {
    unsigned u = __float_as_uint(f);
    u = u + 0x7FFFu + ((u >> 16) & 1u);
    return (unsigned short)(u >> 16);
}
__device__ __forceinline__ float bf2f(unsigned short b) {
    return __uint_as_float(((unsigned)b) << 16);
}

__global__ __launch_bounds__(512, 2) __attribute__((amdgpu_waves_per_eu(2, 2)))
void lstm_rec_coop(const float* __restrict__ xg, const float* __restrict__ w_hh,
                   const float* __restrict__ b_hh, unsigned long long* mbox,
                   float* __restrict__ c_state, float* __restrict__ h_out,
                   int CH, int gbase)
{
    __shared__ __attribute__((aligned(16))) unsigned short hh_hi[2][HID];
    __shared__ __attribute__((aligned(16))) unsigned short hh_lo[2][HID];

    const int s    = blockIdx.x >> 6;
    const int b    = blockIdx.x & 63;
    const int tid  = threadIdx.x;
    const int lane = tid & 63;
    const int wv   = tid >> 6;          // wave 0..7
    const int q    = lane >> 4;         // quad 0..3
    const int mcol = lane & 15;
    const int qoff = q * 8;             // k-offset within a 32-k-tile

    // ---- one-time: gather + split weights into pinned A-fragments ----
    // A-frag (m120-verified): lane supplies A[m=mcol][k = kt*32 + q*8 + j].
    // tile-row m maps to gate (m&3) of unit wv*8 + t*4 + (m>>2).
    short8 wa_hi[2][8], wa_lo[2][8];
    #pragma unroll
    for (int t = 0; t < 2; ++t) {
        const int grow = (mcol & 3) * 256 + s * 64 + (wv * 8 + t * 4 + (mcol >> 2));
        const float* wrow = w_hh + (size_t)grow * HID;
        #pragma unroll
        for (int kt = 0; kt < 8; ++kt) {
            const float* wp = wrow + kt * 32 + qoff;
            float4 w0 = *(const float4*)wp;
            float4 w1 = *(const float4*)(wp + 4);
            float wf[8] = {w0.x, w0.y, w0.z, w0.w, w1.x, w1.y, w1.z, w1.w};
            short8 hi, lo;
            #pragma unroll
            for (int j = 0; j < 8; ++j) {
                unsigned short hb = f2bf_rne(wf[j]);
                hi[j] = (short)hb;
                lo[j] = (short)f2bf_rne(wf[j] - bf2f(hb));
            }
            wa_hi[t][kt] = hi;
            wa_lo[t][kt] = lo;
        }
    }
    asm volatile("" ::: "memory");   // forbid sinking weight loads into t-loop

    // ---- one-time: owner-lane (mcol==0) unit state & biases ----
    const int u0  = wv * 8 + q;        // tile-0 unit
    const int u1  = wv * 8 + 4 + q;    // tile-1 unit
    const int gu0 = s * 64 + u0;
    const int gu1 = s * 64 + u1;
    float c0 = 0.f, c1 = 0.f;
    float bh0[4] = {0.f, 0.f, 0.f, 0.f}, bh1[4] = {0.f, 0.f, 0.f, 0.f};
    if (mcol == 0) {
        c0 = c_state[b * HID + gu0];
        c1 = c_state[b * HID + gu1];
        #pragma unroll
        for (int r = 0; r < 4; ++r) {
            bh0[r] = b_hh[r * 256 + gu0];
            bh1[r] = b_hh[r * 256 + gu1];
        }
    }

    const float* xg_b = xg + (size_t)b * CH * GATES;

    for (int t = 0; t < CH; ++t) {
        const int gt = gbase + t;
        const int pr = gt & 1;

        // ---- owner lanes: prefetch xg before the spin ----
        float x0[4], x1[4];
        if (mcol == 0) {
            const float* xp = xg_b + (size_t)t * GATES;
            #pragma unroll
            for (int r = 0; r < 4; ++r) {
                x0[r] = xp[r * 256 + gu0];
                x1[r] = xp[r * 256 + gu1];
            }
        }

        // ---- poll mailbox, stage bf16 hi/lo h(t-1) into parity LDS buf ----
        if (tid < HID) {
            const unsigned long long* slot =
                mbox + (size_t)pr * MBSTRIDE + b * HID + tid;
            unsigned long long w;
            do {
                w = __hip_atomic_load(slot, __ATOMIC_RELAXED,
                                      __HIP_MEMORY_SCOPE_AGENT);
            } while ((unsigned)(w >> 32) != (unsigned)gt);
            float hv = __uint_as_float((unsigned)w);
            unsigned short hb = f2bf_rne(hv);
            hh_hi[pr][tid] = hb;
            hh_lo[pr][tid] = f2bf_rne(hv - bf2f(hb));
        }
        __syncthreads();   // the ONLY barrier in the step

        // ---- MFMA matvec: 6 independent chains of depth 8 ----
        f32x4 ahh0 = {0.f,0.f,0.f,0.f}, ahl0 = {0.f,0.f,0.f,0.f},
              alh0 = {0.f,0.f,0.f,0.f}, ahh1 = {0.f,0.f,0.f,0.f},
              ahl1 = {0.f,0.f,0.f,0.f}, alh1 = {0.f,0.f,0.f,0.f};
        #pragma unroll
        for (int kt = 0; kt < 8; ++kt) {
            short8 bhi = *(const short8*)&hh_hi[pr][kt * 32 + qoff];
            short8 blo = *(const short8*)&hh_lo[pr][kt * 32 + qoff];
            ahh0 = __builtin_amdgcn_mfma_f32_16x16x32_bf16(wa_hi[0][kt], bhi, ahh0, 0, 0, 0);
            ahh1 = __builtin_amdgcn_mfma_f32_16x16x32_bf16(wa_hi[1][kt], bhi, ahh1, 0, 0, 0);
            ahl0 = __builtin_amdgcn_mfma_f32_16x16x32_bf16(wa_hi[0][kt], blo, ahl0, 0, 0, 0);
            ahl1 = __builtin_amdgcn_mfma_f32_16x16x32_bf16(wa_hi[1][kt], blo, ahl1, 0, 0, 0);
            alh0 = __builtin_amdgcn_mfma_f32_16x16x32_bf16(wa_lo[0][kt], bhi, alh0, 0, 0, 0);
            alh1 = __builtin_amdgcn_mfma_f32_16x16x32_bf16(wa_lo[1][kt], bhi, alh1, 0, 0, 0);
        }

        // ---- in-lane cell update + publish (owner lanes only) ----
        if (mcol == 0) {
            f32x4 g0 = ahh0 + ahl0 + alh0;
            f32x4 g1 = ahh1 + ahl1 + alh1;

            float ig = sigmoid_f(g0[0] + x0[0] + bh0[0]);
            float fg = sigmoid_f(g0[1] + x0[1] + bh0[1]);
            float gv = tanh_f   (g0[2] + x0[2] + bh0[2]);
            float og = sigmoid_f(g0[3] + x0[3] + bh0[3]);
            c0 = fg * c0 + ig * gv;
            float h0 = og * tanh_f(c0);

            ig = sigmoid_f(g1[0] + x1[0] + bh1[0]);
            fg = sigmoid_f(g1[1] + x1[1] + bh1[1]);
            gv = tanh_f   (g1[2] + x1[2] + bh1[2]);
            og = sigmoid_f(g1[3] + x1[3] + bh1[3]);
            c1 = fg * c1 + ig * gv;
            float h1 = og * tanh_f(c1);

            const unsigned long long tagw =
                (unsigned long long)(unsigned)(gt + 1) << 32;
            unsigned long long* mb =
                mbox + (size_t)((gt + 1) & 1) * MBSTRIDE + b * HID;
            __hip_atomic_store(mb + gu0,
                tagw | (unsigned long long)__float_as_uint(h0),
                __ATOMIC_RELAXED, __HIP_MEMORY_SCOPE_AGENT);
            __hip_atomic_store(mb + gu1,
                tagw | (unsigned long long)__float_as_uint(h1),
                __ATOMIC_RELAXED, __HIP_MEMORY_SCOPE_AGENT);

            if (h_out) {
                float* hp = h_out + ((size_t)b * CH + t) * HID;
                hp[gu0] = h0;
                hp[gu1] = h1;
            }
        }
        // no second barrier: parity LDS double-buffer + tag gating make the
        // next iteration's staging writes race-free vs this step's reads.
    }

    if (mcol == 0) {
        c_state[b * HID + gu0] = c0;
        c_state[b * HID + gu1] = c1;
    }
}

// ---------------------------------------------------------------------------
__global__ void final_linear(const unsigned long long* __restrict__ hw,
                             const float* __restrict__ w_lin,
                             const float* __restrict__ b_lin,
                             float* __restrict__ out)
{
    int b = blockIdx.x;
    int l = threadIdx.x;
    float p = 0.f;
    #pragma unroll
    for (int j = 0; j < 4; ++j) {
        int u = l + j * 64;
        p += __uint_as_float((unsigned)hw[b * HID + u]) * w_lin[u];
    }
    #pragma unroll
    for (int off = 32; off > 0; off >>= 1) p += __shfl_down(p, off, 64);
    if (l == 0) out[b] = p + b_lin[0];
}

// ---------------------------------------------------------------------------
extern "C" void kernel_launch(void* const* d_in, const int* in_sizes, int n_in,
                              void* d_out, int out_size, void* d_ws, size_t ws_size,
                              hipStream_t stream)
{
    const float* input = (const float*)d_in[0];
    const float* w_ih  = (const float*)d_in[1];
    const float* w_hh  = (const float*)d_in[2];
    const float* b_ih  = (const float*)d_in[3];
    const float* b_hh  = (const float*)d_in[4];
    const float* w_lin = (const float*)d_in[5];
    const float* b_lin = (const float*)d_in[6];
    float* out = (float*)d_out;

    const size_t c_elems  = (size_t)BATCH * HID;
    const size_t mb_bytes = 2 * MBSTRIDE * sizeof(unsigned long long);
    char*  ws   = (char*)d_ws;
    float* c1st = (float*)ws;
    float* c2st = c1st + c_elems;
    unsigned long long* mb1 = (unsigned long long*)(c2st + c_elems);
    unsigned long long* mb2 = mb1 + 2 * MBSTRIDE;
    const size_t zero_bytes = 2 * c_elems * 4 + 2 * mb_bytes;
    float* big  = (float*)(ws + ((zero_bytes + 255) & ~(size_t)255));

    int CH = 128;
    while (CH > 16) {
        size_t need = ((zero_bytes + 255) & ~(size_t)255)
                    + ((size_t)2 * BATCH * CH * GATES + (size_t)BATCH * CH * HID) * 4;
        if (need <= ws_size) break;
        CH >>= 1;
    }
    const int ch_log2 = __builtin_ctz((unsigned)CH);

    float* xg1  = big;
    float* xg2  = xg1 + (size_t)BATCH * CH * GATES;
    float* h1ch = xg2 + (size_t)BATCH * CH * GATES;

    hipMemsetAsync(ws, 0, zero_bytes, stream);

    const int NC = SEQ / CH;
    dim3 gblk(BATCH * CH / BM, GATES / BN);

    for (int c = 0; c < NC; ++c) {
        xg_gemm<<<gblk, 256, 0, stream>>>(input + (size_t)c * CH * HID, w_ih,
                                          b_ih, xg1, SEQ * HID, ch_log2);
        lstm_rec_coop<<<256, 512, 0, stream>>>(xg1, w_hh, b_hh, mb1,
                                               c1st, h1ch, CH, c * CH);
        xg_gemm<<<gblk, 256, 0, stream>>>(h1ch, w_ih + GATES * HID,
                                          b_ih + GATES, xg2, CH * HID, ch_log2);
        lstm_rec_coop<<<256, 512, 0, stream>>>(xg2, w_hh + (size_t)GATES * HID,
                                               b_hh + GATES, mb2,
                                               c2st, nullptr, CH, c * CH);
    }

    // last h2 (step 2047, tag 2048) sits in mb2 parity-0 block
    final_linear<<<BATCH, 64, 0, stream>>>(mb2, w_lin, b_lin, out);
}

// Round 7
// 7640.948 us; speedup vs baseline: 1.4263x; 1.4263x over previous
//
#include <hip/hip_runtime.h>
#include <math.h>

#define HID   256
#define GATES 1024   // 4*HID
#define BATCH 64
#define SEQ   2048

// ---------------------------------------------------------------------------
// GEMM: out[r][g] = sum_k A_row(r)[k] * W[g][k] + bias[g]   (unchanged)
// ---------------------------------------------------------------------------
#define BM 128
#define BN 128
#define BK 16
#define LDP 132

__global__ __launch_bounds__(256, 2)
void xg_gemm(const float* __restrict__ A, const float* __restrict__ W,
             const float* __restrict__ bias, float* __restrict__ out,
             int a_bstride, int ch_log2)
{
    __shared__ float As[BK][LDP];
    __shared__ float Ws[BK][LDP];

    const int tid   = threadIdx.x;
    const int m_blk = blockIdx.x * BM;
    const int n_blk = blockIdx.y * BN;

    const int tn = (tid & 15) * 4;
    const int tm = (tid >> 4) * 4;

    float acc[8][8];
    #pragma unroll
    for (int i = 0; i < 8; ++i)
        #pragma unroll
        for (int j = 0; j < 8; ++j) acc[i][j] = 0.f;

    const int lrow = tid >> 2;
    const int lkc  = (tid & 3) * 4;
    const int CHm1 = (1 << ch_log2) - 1;

    for (int k0 = 0; k0 < HID; k0 += BK) {
        #pragma unroll
        for (int p = 0; p < 2; ++p) {
            int row = p * 64 + lrow;
            int r   = m_blk + row;
            int b   = r >> ch_log2;
            int t   = r & CHm1;
            const float4 a = *(const float4*)(A + (size_t)b * a_bstride +
                                              (size_t)t * HID + k0 + lkc);
            As[lkc + 0][row] = a.x;
            As[lkc + 1][row] = a.y;
            As[lkc + 2][row] = a.z;
            As[lkc + 3][row] = a.w;

            int g = n_blk + row;
            const float4 w = *(const float4*)(W + (size_t)g * HID + k0 + lkc);
            Ws[lkc + 0][row] = w.x;
            Ws[lkc + 1][row] = w.y;
            Ws[lkc + 2][row] = w.z;
            Ws[lkc + 3][row] = w.w;
        }
        __syncthreads();

        #pragma unroll
        for (int kk = 0; kk < BK; ++kk) {
            float4 a0 = *(const float4*)&As[kk][tm];
            float4 a1 = *(const float4*)&As[kk][tm + 64];
            float4 b0 = *(const float4*)&Ws[kk][tn];
            float4 b1 = *(const float4*)&Ws[kk][tn + 64];
            float av[8] = {a0.x, a0.y, a0.z, a0.w, a1.x, a1.y, a1.z, a1.w};
            float bv[8] = {b0.x, b0.y, b0.z, b0.w, b1.x, b1.y, b1.z, b1.w};
            #pragma unroll
            for (int i = 0; i < 8; ++i)
                #pragma unroll
                for (int j = 0; j < 8; ++j)
                    acc[i][j] += av[i] * bv[j];
        }
        __syncthreads();
    }

    const float4 bias0 = *(const float4*)&bias[n_blk + tn];
    const float4 bias1 = *(const float4*)&bias[n_blk + tn + 64];
    #pragma unroll
    for (int i = 0; i < 8; ++i) {
        int m  = (i < 4) ? (tm + i) : (tm + 60 + i);
        int gm = m_blk + m;
        float* op = out + (size_t)gm * GATES + n_blk;
        float4 v0 = {acc[i][0] + bias0.x, acc[i][1] + bias0.y,
                     acc[i][2] + bias0.z, acc[i][3] + bias0.w};
        float4 v1 = {acc[i][4] + bias1.x, acc[i][5] + bias1.y,
                     acc[i][6] + bias1.z, acc[i][7] + bias1.w};
        *(float4*)(op + tn)      = v0;
        *(float4*)(op + tn + 64) = v1;
    }
}

// ---------------------------------------------------------------------------
// Cooperative recurrence v6: fp32 VALU matvec with TRULY pinned weights.
// 256 wgs (slice s=0..3, batch b), 1024 threads (16 waves, 1 wg/CU).
// Thread tid: gate row r=tid>>2 (wg-local, 0..255), k-quarter q=tid&3.
// Row map: r = 4*unit + gate  ->  global row (r&3)*256 + s*64 + (r>>2),
// so owner tid<64 reads its unit's 4 gates as one float4 from g_s[4u].
// Weights: 16 float4 = 64 VGPRs, laundered via asm("+v") after load so the
// compiler CANNOT re-materialize them from memory (R4/R5/R6 failure mode).
// 64 + ~45 working regs < 128 cap (launch_bounds(1024,4)) -> no spill.
// h staging: parity-double-buffered LDS, padded 68-float quarters so the 4
// broadcast addresses per wave hit disjoint bank groups. 2 barriers/step.
// Sibling exchange: R4's single-atom (tag<<32|h) parity mailbox, unchanged.
// ---------------------------------------------------------------------------
#define MBSTRIDE ((size_t)BATCH * HID)   // ulongs per parity block

__device__ __forceinline__ float sigmoid_f(float x) {
    return 1.f / (1.f + __expf(-x));
}
__device__ __forceinline__ float tanh_f(float x) {
    return 1.f - 2.f / (1.f + __expf(2.f * x));
}

__global__ __launch_bounds__(1024, 4)
void lstm_rec_coop(const float* __restrict__ xg, const float* __restrict__ w_hh,
                   const float* __restrict__ b_hh, unsigned long long* mbox,
                   float* __restrict__ c_state, float* __restrict__ h_out,
                   int CH, int gbase)
{
    // parity-buffered h, quarters padded to 68 floats (bank-group disjoint)
    __shared__ __attribute__((aligned(16))) float hsh[2][4 * 68];
    __shared__ __attribute__((aligned(16))) float g_s[256];

    const int s   = blockIdx.x >> 6;
    const int b   = blockIdx.x & 63;
    const int tid = threadIdx.x;
    const int r   = tid >> 2;            // wg-local gate row 0..255
    const int q   = tid & 3;             // k-quarter

    // global gate row: gate (r&3) of unit (r>>2) in slice s
    const int grow = (r & 3) * 256 + s * 64 + (r >> 2);

    // ---- one-time: pin 64 weight floats in VGPRs, launder so they stay ----
    float4 wreg[16];
    {
        const float4* wr = (const float4*)(w_hh + (size_t)grow * HID + q * 64);
        #pragma unroll
        for (int j = 0; j < 16; ++j) {
            float4 w = wr[j];
            asm volatile("" : "+v"(w.x), "+v"(w.y), "+v"(w.z), "+v"(w.w));
            wreg[j] = w;
        }
    }

    // ---- one-time: owner (tid<64) unit state & biases ----
    const int u  = tid;                  // unit (valid tid<64)
    const int gu = s * 64 + u;
    float c_u = 0.f;
    float bh[4] = {0.f, 0.f, 0.f, 0.f};
    if (tid < 64) {
        c_u = c_state[b * HID + gu];
        #pragma unroll
        for (int g = 0; g < 4; ++g) bh[g] = b_hh[g * 256 + gu];
    }

    const float* xg_b = xg + (size_t)b * CH * GATES;

    for (int t = 0; t < CH; ++t) {
        const int gt = gbase + t;
        const int pr = gt & 1;

        // ---- owners: prefetch xg before the spin ----
        float xv[4];
        if (tid < 64) {
            const float* xp = xg_b + (size_t)t * GATES;
            #pragma unroll
            for (int g = 0; g < 4; ++g) xv[g] = xp[g * 256 + gu];
        }

        // ---- poll mailbox (tag==gt), stage h(t-1) into parity LDS ----
        if (tid < HID) {
            const unsigned long long* slot =
                mbox + (size_t)pr * MBSTRIDE + b * HID + tid;
            unsigned long long w;
            do {
                w = __hip_atomic_load(slot, __ATOMIC_RELAXED,
                                      __HIP_MEMORY_SCOPE_AGENT);
            } while ((unsigned)(w >> 32) != (unsigned)gt);
            hsh[pr][(tid >> 6) * 68 + (tid & 63)] = __uint_as_float((unsigned)w);
        }
        __syncthreads();   // barrier 1: hsh ready (also fences g_s reuse)

        // ---- matvec: row r, quarter q (64 pinned weights x LDS broadcast) --
        {
            const float4* hq = (const float4*)&hsh[pr][q * 68];
            float acc = 0.f;
            #pragma unroll
            for (int j = 0; j < 16; ++j) {
                float4 hh = hq[j];
                acc += wreg[j].x * hh.x + wreg[j].y * hh.y
                     + wreg[j].z * hh.z + wreg[j].w * hh.w;
            }
            acc += __shfl_xor(acc, 1, 64);
            acc += __shfl_xor(acc, 2, 64);
            if (q == 0) g_s[r] = acc;
        }
        __syncthreads();   // barrier 2: g_s ready

        // ---- owners: cell update + publish ----
        if (tid < 64) {
            float4 g4 = *(const float4*)&g_s[4 * u];   // gates i,f,g,o of unit u
            float ig = sigmoid_f(g4.x + xv[0] + bh[0]);
            float fg = sigmoid_f(g4.y + xv[1] + bh[1]);
            float gv = tanh_f   (g4.z + xv[2] + bh[2]);
            float og = sigmoid_f(g4.w + xv[3] + bh[3]);
            c_u = fg * c_u + ig * gv;
            float h = og * tanh_f(c_u);

            __hip_atomic_store(
                mbox + (size_t)((gt + 1) & 1) * MBSTRIDE + b * HID + gu,
                ((unsigned long long)(unsigned)(gt + 1) << 32) |
                    (unsigned long long)__float_as_uint(h),
                __ATOMIC_RELAXED, __HIP_MEMORY_SCOPE_AGENT);

            if (h_out) h_out[((size_t)b * CH + t) * HID + gu] = h;
        }
        // no third barrier: hsh is parity-buffered; g_s(t) readers are the
        // owners themselves, and the next g_s write is after barrier 1(t+1).
    }

    if (tid < 64) c_state[b * HID + gu] = c_u;
}

// ---------------------------------------------------------------------------
__global__ void final_linear(const unsigned long long* __restrict__ hw,
                             const float* __restrict__ w_lin,
                             const float* __restrict__ b_lin,
                             float* __restrict__ out)
{
    int b = blockIdx.x;
    int l = threadIdx.x;
    float p = 0.f;
    #pragma unroll
    for (int j = 0; j < 4; ++j) {
        int u = l + j * 64;
        p += __uint_as_float((unsigned)hw[b * HID + u]) * w_lin[u];
    }
    #pragma unroll
    for (int off = 32; off > 0; off >>= 1) p += __shfl_down(p, off, 64);
    if (l == 0) out[b] = p + b_lin[0];
}

// ---------------------------------------------------------------------------
extern "C" void kernel_launch(void* const* d_in, const int* in_sizes, int n_in,
                              void* d_out, int out_size, void* d_ws, size_t ws_size,
                              hipStream_t stream)
{
    const float* input = (const float*)d_in[0];
    const float* w_ih  = (const float*)d_in[1];
    const float* w_hh  = (const float*)d_in[2];
    const float* b_ih  = (const float*)d_in[3];
    const float* b_hh  = (const float*)d_in[4];
    const float* w_lin = (const float*)d_in[5];
    const float* b_lin = (const float*)d_in[6];
    float* out = (float*)d_out;

    const size_t c_elems  = (size_t)BATCH * HID;
    const size_t mb_bytes = 2 * MBSTRIDE * sizeof(unsigned long long);
    char*  ws   = (char*)d_ws;
    float* c1st = (float*)ws;
    float* c2st = c1st + c_elems;
    unsigned long long* mb1 = (unsigned long long*)(c2st + c_elems);
    unsigned long long* mb2 = mb1 + 2 * MBSTRIDE;
    const size_t zero_bytes = 2 * c_elems * 4 + 2 * mb_bytes;
    float* big  = (float*)(ws + ((zero_bytes + 255) & ~(size_t)255));

    int CH = 128;
    while (CH > 16) {
        size_t need = ((zero_bytes + 255) & ~(size_t)255)
                    + ((size_t)2 * BATCH * CH * GATES + (size_t)BATCH * CH * HID) * 4;
        if (need <= ws_size) break;
        CH >>= 1;
    }
    const int ch_log2 = __builtin_ctz((unsigned)CH);

    float* xg1  = big;
    float* xg2  = xg1 + (size_t)BATCH * CH * GATES;
    float* h1ch = xg2 + (size_t)BATCH * CH * GATES;

    hipMemsetAsync(ws, 0, zero_bytes, stream);

    const int NC = SEQ / CH;
    dim3 gblk(BATCH * CH / BM, GATES / BN);

    for (int c = 0; c < NC; ++c) {
        xg_gemm<<<gblk, 256, 0, stream>>>(input + (size_t)c * CH * HID, w_ih,
                                          b_ih, xg1, SEQ * HID, ch_log2);
        lstm_rec_coop<<<256, 1024, 0, stream>>>(xg1, w_hh, b_hh, mb1,
                                                c1st, h1ch, CH, c * CH);
        xg_gemm<<<gblk, 256, 0, stream>>>(h1ch, w_ih + GATES * HID,
                                          b_ih + GATES, xg2, CH * HID, ch_log2);
        lstm_rec_coop<<<256, 1024, 0, stream>>>(xg2, w_hh + (size_t)GATES * HID,
                                                b_hh + GATES, mb2,
                                                c2st, nullptr, CH, c * CH);
    }

    // last h2 (step 2047, tag 2048) sits in mb2 parity-0 block
    final_linear<<<BATCH, 64, 0, stream>>>(mb2, w_lin, b_lin, out);
}

// Round 8
// 7561.022 us; speedup vs baseline: 1.4414x; 1.0106x over previous
//
#include <hip/hip_runtime.h>
#include <math.h>

#define HID   256
#define GATES 1024   // 4*HID
#define BATCH 64
#define SEQ   2048

// ---------------------------------------------------------------------------
// GEMM: out[r][g] = sum_k A_row(r)[k] * W[g][k] + bias[g]   (unchanged)
// ---------------------------------------------------------------------------
#define BM 128
#define BN 128
#define BK 16
#define LDP 132

__global__ __launch_bounds__(256, 2)
void xg_gemm(const float* __restrict__ A, const float* __restrict__ W,
             const float* __restrict__ bias, float* __restrict__ out,
             int a_bstride, int ch_log2)
{
    __shared__ float As[BK][LDP];
    __shared__ float Ws[BK][LDP];

    const int tid   = threadIdx.x;
    const int m_blk = blockIdx.x * BM;
    const int n_blk = blockIdx.y * BN;

    const int tn = (tid & 15) * 4;
    const int tm = (tid >> 4) * 4;

    float acc[8][8];
    #pragma unroll
    for (int i = 0; i < 8; ++i)
        #pragma unroll
        for (int j = 0; j < 8; ++j) acc[i][j] = 0.f;

    const int lrow = tid >> 2;
    const int lkc  = (tid & 3) * 4;
    const int CHm1 = (1 << ch_log2) - 1;

    for (int k0 = 0; k0 < HID; k0 += BK) {
        #pragma unroll
        for (int p = 0; p < 2; ++p) {
            int row = p * 64 + lrow;
            int r   = m_blk + row;
            int b   = r >> ch_log2;
            int t   = r & CHm1;
            const float4 a = *(const float4*)(A + (size_t)b * a_bstride +
                                              (size_t)t * HID + k0 + lkc);
            As[lkc + 0][row] = a.x;
            As[lkc + 1][row] = a.y;
            As[lkc + 2][row] = a.z;
            As[lkc + 3][row] = a.w;

            int g = n_blk + row;
            const float4 w = *(const float4*)(W + (size_t)g * HID + k0 + lkc);
            Ws[lkc + 0][row] = w.x;
            Ws[lkc + 1][row] = w.y;
            Ws[lkc + 2][row] = w.z;
            Ws[lkc + 3][row] = w.w;
        }
        __syncthreads();

        #pragma unroll
        for (int kk = 0; kk < BK; ++kk) {
            float4 a0 = *(const float4*)&As[kk][tm];
            float4 a1 = *(const float4*)&As[kk][tm + 64];
            float4 b0 = *(const float4*)&Ws[kk][tn];
            float4 b1 = *(const float4*)&Ws[kk][tn + 64];
            float av[8] = {a0.x, a0.y, a0.z, a0.w, a1.x, a1.y, a1.z, a1.w};
            float bv[8] = {b0.x, b0.y, b0.z, b0.w, b1.x, b1.y, b1.z, b1.w};
            #pragma unroll
            for (int i = 0; i < 8; ++i)
                #pragma unroll
                for (int j = 0; j < 8; ++j)
                    acc[i][j] += av[i] * bv[j];
        }
        __syncthreads();
    }

    const float4 bias0 = *(const float4*)&bias[n_blk + tn];
    const float4 bias1 = *(const float4*)&bias[n_blk + tn + 64];
    #pragma unroll
    for (int i = 0; i < 8; ++i) {
        int m  = (i < 4) ? (tm + i) : (tm + 60 + i);
        int gm = m_blk + m;
        float* op = out + (size_t)gm * GATES + n_blk;
        float4 v0 = {acc[i][0] + bias0.x, acc[i][1] + bias0.y,
                     acc[i][2] + bias0.z, acc[i][3] + bias0.w};
        float4 v1 = {acc[i][4] + bias1.x, acc[i][5] + bias1.y,
                     acc[i][6] + bias1.z, acc[i][7] + bias1.w};
        *(float4*)(op + tn)      = v0;
        *(float4*)(op + tn + 64) = v1;
    }
}

// ---------------------------------------------------------------------------
// Cooperative recurrence v7: register h-reuse (4 rows x 16 k per thread).
// 256 wgs (slice s=0..3, batch b), 1024 threads, 1 wg/CU.
// Thread (kc=tid&15, u=tid>>4) owns gates i,f,g,o of unit u over k-range
// [16kc,16kc+16): reads 16 h floats from LDS, reuses each across 4 rows ->
// per-step LDS broadcast traffic 256KB -> 64KB (R4/R7's measured 1.5us/step
// floor was this traffic: 2048cyc at 128B/cyc + sync).
// Partials: one ds_write_b128 to part[kc][4u..4u+3]; owner wave (tid<64)
// sums 16 float4s -> 4 gates in-register, cell update, publish.
// Weights: 16 float4 = 64 regs/thread, laundered; sibling exchange = R4's
// single-atom (tag<<32|h) parity mailbox, 2 barriers/step.
// ---------------------------------------------------------------------------
#define MBSTRIDE ((size_t)BATCH * HID)   // ulongs per parity block

__device__ __forceinline__ float sigmoid_f(float x) {
    return 1.f / (1.f + __expf(-x));
}
__device__ __forceinline__ float tanh_f(float x) {
    return 1.f - 2.f / (1.f + __expf(2.f * x));
}

__global__ __launch_bounds__(1024, 4)
void lstm_rec_coop(const float* __restrict__ xg, const float* __restrict__ w_hh,
                   const float* __restrict__ b_hh, unsigned long long* mbox,
                   float* __restrict__ c_state, float* __restrict__ h_out,
                   int CH, int gbase)
{
    // h staged per parity; 16-float chunks padded to 20 (bank-spread, 16B-aligned)
    __shared__ __attribute__((aligned(16))) float hsh[2][16 * 20];
    // partials: part[kc][4u+j] = gate j of unit u, k-chunk kc (260 pad: 16B-aligned rows)
    __shared__ __attribute__((aligned(16))) float part[16][260];

    const int s   = blockIdx.x >> 6;
    const int b   = blockIdx.x & 63;
    const int tid = threadIdx.x;
    const int kc  = tid & 15;            // k-chunk
    const int u   = tid >> 4;            // unit 0..63

    // ---- one-time: 4 gate-rows x 16 weights into registers, laundered ----
    float4 wreg[4][4];
    #pragma unroll
    for (int j = 0; j < 4; ++j) {
        const float* wr = w_hh + (size_t)(j * 256 + s * 64 + u) * HID + kc * 16;
        #pragma unroll
        for (int i = 0; i < 4; ++i) {
            float4 w = *(const float4*)(wr + 4 * i);
            asm volatile("" : "+v"(w.x), "+v"(w.y), "+v"(w.z), "+v"(w.w));
            wreg[j][i] = w;
        }
    }

    // ---- one-time: owner (tid<64) unit state & biases ----
    const int gu = s * 64 + tid;         // valid for tid<64
    float c_u = 0.f;
    float bh[4] = {0.f, 0.f, 0.f, 0.f};
    if (tid < 64) {
        c_u = c_state[b * HID + gu];
        #pragma unroll
        for (int g = 0; g < 4; ++g) bh[g] = b_hh[g * 256 + gu];
    }

    const float* xg_b = xg + (size_t)b * CH * GATES;

    for (int t = 0; t < CH; ++t) {
        const int gt = gbase + t;
        const int pr = gt & 1;

        // ---- owners: prefetch xg before the spin ----
        float xv[4];
        if (tid < 64) {
            const float* xp = xg_b + (size_t)t * GATES;
            #pragma unroll
            for (int g = 0; g < 4; ++g) xv[g] = xp[g * 256 + gu];
        }

        // ---- poll mailbox (tag==gt), stage h(t-1) into parity LDS ----
        if (tid < HID) {
            const unsigned long long* slot =
                mbox + (size_t)pr * MBSTRIDE + b * HID + tid;
            unsigned long long w;
            do {
                w = __hip_atomic_load(slot, __ATOMIC_RELAXED,
                                      __HIP_MEMORY_SCOPE_AGENT);
            } while ((unsigned)(w >> 32) != (unsigned)gt);
            hsh[pr][(tid >> 4) * 20 + (tid & 15)] = __uint_as_float((unsigned)w);
        }
        __syncthreads();   // barrier 1: hsh ready (also fences part reuse)

        // ---- matvec: 16 h floats, reused across 4 gate rows ----
        {
            const float4* hq = (const float4*)&hsh[pr][kc * 20];
            float4 h0 = hq[0], h1 = hq[1], h2 = hq[2], h3 = hq[3];
            float4 pv;
            float* pp = (float*)&pv;
            #pragma unroll
            for (int j = 0; j < 4; ++j) {
                float a = wreg[j][0].x * h0.x + wreg[j][0].y * h0.y
                        + wreg[j][0].z * h0.z + wreg[j][0].w * h0.w;
                a += wreg[j][1].x * h1.x + wreg[j][1].y * h1.y
                   + wreg[j][1].z * h1.z + wreg[j][1].w * h1.w;
                a += wreg[j][2].x * h2.x + wreg[j][2].y * h2.y
                   + wreg[j][2].z * h2.z + wreg[j][2].w * h2.w;
                a += wreg[j][3].x * h3.x + wreg[j][3].y * h3.y
                   + wreg[j][3].z * h3.z + wreg[j][3].w * h3.w;
                pp[j] = a;
            }
            *(float4*)&part[kc][4 * u] = pv;
        }
        __syncthreads();   // barrier 2: partials ready

        // ---- owners: reduce 16 chunks, cell update, publish ----
        if (tid < 64) {
            float gx = 0.f, gy = 0.f, gz = 0.f, gw = 0.f;
            #pragma unroll
            for (int k = 0; k < 16; ++k) {
                float4 pk = *(const float4*)&part[k][4 * tid];
                gx += pk.x; gy += pk.y; gz += pk.z; gw += pk.w;
            }
            float ig = sigmoid_f(gx + xv[0] + bh[0]);
            float fg = sigmoid_f(gy + xv[1] + bh[1]);
            float gv = tanh_f   (gz + xv[2] + bh[2]);
            float og = sigmoid_f(gw + xv[3] + bh[3]);
            c_u = fg * c_u + ig * gv;
            float h = og * tanh_f(c_u);

            __hip_atomic_store(
                mbox + (size_t)((gt + 1) & 1) * MBSTRIDE + b * HID + gu,
                ((unsigned long long)(unsigned)(gt + 1) << 32) |
                    (unsigned long long)__float_as_uint(h),
                __ATOMIC_RELAXED, __HIP_MEMORY_SCOPE_AGENT);

            if (h_out) h_out[((size_t)b * CH + t) * HID + gu] = h;
        }
        // no third barrier: part(t+1) writes happen only after barrier 1(t+1),
        // which owners reach only after finishing their part(t) reads; hsh is
        // parity-buffered.
    }

    if (tid < 64) c_state[b * HID + gu] = c_u;
}

// ---------------------------------------------------------------------------
__global__ void final_linear(const unsigned long long* __restrict__ hw,
                             const float* __restrict__ w_lin,
                             const float* __restrict__ b_lin,
                             float* __restrict__ out)
{
    int b = blockIdx.x;
    int l = threadIdx.x;
    float p = 0.f;
    #pragma unroll
    for (int j = 0; j < 4; ++j) {
        int u = l + j * 64;
        p += __uint_as_float((unsigned)hw[b * HID + u]) * w_lin[u];
    }
    #pragma unroll
    for (int off = 32; off > 0; off >>= 1) p += __shfl_down(p, off, 64);
    if (l == 0) out[b] = p + b_lin[0];
}

// ---------------------------------------------------------------------------
extern "C" void kernel_launch(void* const* d_in, const int* in_sizes, int n_in,
                              void* d_out, int out_size, void* d_ws, size_t ws_size,
                              hipStream_t stream)
{
    const float* input = (const float*)d_in[0];
    const float* w_ih  = (const float*)d_in[1];
    const float* w_hh  = (const float*)d_in[2];
    const float* b_ih  = (const float*)d_in[3];
    const float* b_hh  = (const float*)d_in[4];
    const float* w_lin = (const float*)d_in[5];
    const float* b_lin = (const float*)d_in[6];
    float* out = (float*)d_out;

    const size_t c_elems  = (size_t)BATCH * HID;
    const size_t mb_bytes = 2 * MBSTRIDE * sizeof(unsigned long long);
    char*  ws   = (char*)d_ws;
    float* c1st = (float*)ws;
    float* c2st = c1st + c_elems;
    unsigned long long* mb1 = (unsigned long long*)(c2st + c_elems);
    unsigned long long* mb2 = mb1 + 2 * MBSTRIDE;
    const size_t zero_bytes = 2 * c_elems * 4 + 2 * mb_bytes;
    float* big  = (float*)(ws + ((zero_bytes + 255) & ~(size_t)255));

    int CH = 256;   // fit-checked; falls back if ws_size is smaller
    while (CH > 16) {
        size_t need = ((zero_bytes + 255) & ~(size_t)255)
                    + ((size_t)2 * BATCH * CH * GATES + (size_t)BATCH * CH * HID) * 4;
        if (need <= ws_size) break;
        CH >>= 1;
    }
    const int ch_log2 = __builtin_ctz((unsigned)CH);

    float* xg1  = big;
    float* xg2  = xg1 + (size_t)BATCH * CH * GATES;
    float* h1ch = xg2 + (size_t)BATCH * CH * GATES;

    hipMemsetAsync(ws, 0, zero_bytes, stream);

    const int NC = SEQ / CH;
    dim3 gblk(BATCH * CH / BM, GATES / BN);

    for (int c = 0; c < NC; ++c) {
        xg_gemm<<<gblk, 256, 0, stream>>>(input + (size_t)c * CH * HID, w_ih,
                                          b_ih, xg1, SEQ * HID, ch_log2);
        lstm_rec_coop<<<256, 1024, 0, stream>>>(xg1, w_hh, b_hh, mb1,
                                                c1st, h1ch, CH, c * CH);
        xg_gemm<<<gblk, 256, 0, stream>>>(h1ch, w_ih + GATES * HID,
                                          b_ih + GATES, xg2, CH * HID, ch_log2);
        lstm_rec_coop<<<256, 1024, 0, stream>>>(xg2, w_hh + (size_t)GATES * HID,
                                                b_hh + GATES, mb2,
                                                c2st, nullptr, CH, c * CH);
    }

    // last h2 (step 2047, tag 2048) sits in mb2 parity-0 block
    final_linear<<<BATCH, 64, 0, stream>>>(mb2, w_lin, b_lin, out);
}